// Round 7
// baseline (5125.037 us; speedup 1.0000x reference)
//
#include <hip/hip_runtime.h>

// GraphSAGE-CF on MI355X — round 6.
// Round-5 profile: transform 392us/layer, VALUBusy 58% (~227us issue) of
// which only ~31us is GEMM — the gather's per-edge segmentation bookkeeping
// (~10-12 VALU/edge: validity+flush compares, row-advance loop) dominates.
// This round: pack the 6-bit row-local id into edges.x high bits (col needs
// only 18). Gather loop becomes checkless: hv=hsrc[(x&0x3FFFF)*64+ln];
// ds_add(&Xs[(x>>18)*68+ln], w*hv). Exact floor-split chains (len diff <=1):
// branchless main loop + one masked epilogue iteration. Edges padded +8 so
// prefetch never faults; masked iter clamps e.x (poison-safe).
//
// ws layout (4-byte words):
//   WuT[2][128][64] @0   WiT @16384          Wt[l][k][j]=W[l][j][k]
//   hu1[200000][64]                          layer-0 user out
//   hi1[100000][64]                          layer-0 item out
//   edges_u uint2[3.2M+8]                    (rl<<18|col, w bits) by user row
//   edges_i uint2[3.2M+8]
//   rank_u ushort[3.2M]  rank_i ushort[3.2M]
//   rowptr_u[200001]  rowptr_i[100001]
//   deg_u[200000]  deg_i[100000]
//   bsum_u[782] bpre_u[782] bsum_i[391] bpre_i[391]

#define N_USERS 200000
#define N_ITEMS 100000
#define N_EDGES 3200000
#define NB_U 782      // ceil(200000/256)
#define NB_I 391      // ceil(100000/256)

// ---------- W convert + transpose:  Wt[l][k][j] = W[l][j][k] ----------
__global__ __launch_bounds__(256) void wprep_kernel(
    const float* __restrict__ Wu, const float* __restrict__ Wi,
    float* __restrict__ WuT, float* __restrict__ WiT)
{
    int idx = blockIdx.x * 256 + threadIdx.x;     // 0..32767
    const float* src = Wu;
    float* dst = WuT;
    int i = idx;
    if (idx >= 16384) { src = Wi; dst = WiT; i = idx - 16384; }
    int l = i >> 13;
    int r = i & 8191;
    int j = r >> 7;           // out col 0..63
    int k = r & 127;          // in  idx 0..127
    dst[l * 8192 + k * 64 + j] = src[i];
}

// ---------- degree histogram + per-edge rank (atomic return is the rank) ----
__global__ __launch_bounds__(256) void hist_kernel(
    const int* __restrict__ u_idx, const int* __restrict__ i_idx,
    int* __restrict__ deg_u, int* __restrict__ deg_i,
    unsigned short* __restrict__ rank_u, unsigned short* __restrict__ rank_i)
{
    int t = blockIdx.x * 256 + threadIdx.x;     // < 2E
    if (t < N_EDGES) {
        rank_u[t] = (unsigned short)atomicAdd(&deg_u[u_idx[t]], 1);
    } else {
        int e = t - N_EDGES;
        rank_i[e] = (unsigned short)atomicAdd(&deg_i[i_idx[e]], 1);
    }
}

// ---------- scan phase A: per-block sums ----------
__global__ __launch_bounds__(256) void scanA_kernel(
    const int* __restrict__ deg_u, const int* __restrict__ deg_i,
    int* __restrict__ bsum_u, int* __restrict__ bsum_i)
{
    int b = blockIdx.x;
    const int* deg; int n; int* bs; int bb;
    if (b < NB_U) { deg = deg_u; n = N_USERS; bs = bsum_u; bb = b; }
    else          { deg = deg_i; n = N_ITEMS; bs = bsum_i; bb = b - NB_U; }
    int i = bb * 256 + threadIdx.x;
    int v = (i < n) ? deg[i] : 0;
    #pragma unroll
    for (int off = 1; off < 64; off <<= 1) v += __shfl_xor(v, off);
    __shared__ int ws4[4];
    int wv = threadIdx.x >> 6;
    if ((threadIdx.x & 63) == 0) ws4[wv] = v;
    __syncthreads();
    if (threadIdx.x == 0) bs[bb] = ws4[0] + ws4[1] + ws4[2] + ws4[3];
}

// ---------- scan phase B: exclusive scan of block sums ----------
__global__ __launch_bounds__(1024) void scanB_kernel(
    const int* __restrict__ bsum_u, int* __restrict__ bpre_u,
    const int* __restrict__ bsum_i, int* __restrict__ bpre_i)
{
    __shared__ int s[1024];
    const int* src; int* dst; int n;
    if (blockIdx.x == 0) { src = bsum_u; dst = bpre_u; n = NB_U; }
    else                 { src = bsum_i; dst = bpre_i; n = NB_I; }
    int t = threadIdx.x;
    int v = (t < n) ? src[t] : 0;
    s[t] = v; __syncthreads();
    #pragma unroll
    for (int off = 1; off < 1024; off <<= 1) {
        int x = (t >= off) ? s[t - off] : 0;
        __syncthreads();
        s[t] += x;
        __syncthreads();
    }
    if (t < n) dst[t] = s[t] - v;   // exclusive
}

// ---------- scan phase C: rowptr = bpre + intra-block exclusive ----------
__global__ __launch_bounds__(256) void scanC_kernel(
    const int* __restrict__ deg_u, const int* __restrict__ deg_i,
    const int* __restrict__ bpre_u, const int* __restrict__ bpre_i,
    int* __restrict__ rowptr_u, int* __restrict__ rowptr_i)
{
    int b = blockIdx.x;
    const int* deg; int n; const int* bpre; int* rowptr; int bb;
    if (b < NB_U) { deg = deg_u; n = N_USERS; bpre = bpre_u; rowptr = rowptr_u; bb = b; }
    else          { deg = deg_i; n = N_ITEMS; bpre = bpre_i; rowptr = rowptr_i; bb = b - NB_U; }
    int t = threadIdx.x;
    int i = bb * 256 + t;
    int d = (i < n) ? deg[i] : 0;
    __shared__ int s[256];
    s[t] = d; __syncthreads();
    #pragma unroll
    for (int off = 1; off < 256; off <<= 1) {
        int x = (t >= off) ? s[t - off] : 0;
        __syncthreads();
        s[t] += x;
        __syncthreads();
    }
    int val = bpre[bb] + (s[t] - d);
    if (i < n) rowptr[i] = val;
    if (b == 0 && t == 0) { rowptr_u[N_USERS] = N_EDGES; rowptr_i[N_ITEMS] = N_EDGES; }
}

// ---------- CSR fill: no atomics; XCD-partitioned by destination row ----------
// edges.x = (row & 63) << 18 | col   (col <= 200000 < 2^18)
__global__ __launch_bounds__(256) void fill_kernel(
    const int* __restrict__ u_idx, const int* __restrict__ i_idx,
    const float* __restrict__ w_u2i, const float* __restrict__ w_i2u,
    const unsigned short* __restrict__ rank_u, const unsigned short* __restrict__ rank_i,
    const int* __restrict__ rowptr_u, const int* __restrict__ rowptr_i,
    uint2* __restrict__ edges_u, uint2* __restrict__ edges_i)
{
    const int part   = blockIdx.x & 7;
    const int slot   = blockIdx.x >> 3;
    const int nslots = gridDim.x >> 3;
    const int stride = nslots * 256;

    for (int e = slot * 256 + threadIdx.x; e < N_EDGES; e += stride) {
        int ru = u_idx[e];
        int ri = i_idx[e];
        if ((ru & 7) == part) {
            int p = rowptr_u[ru] + rank_u[e];
            edges_u[p] = make_uint2((unsigned)ri | ((unsigned)(ru & 63) << 18),
                                    __float_as_uint(w_u2i[e]));
        }
        if ((ri & 7) == part) {
            int p = rowptr_i[ri] + rank_i[e];
            edges_i[p] = make_uint2((unsigned)ru | ((unsigned)(ri & 63) << 18),
                                    __float_as_uint(w_i2u[e]));
        }
    }
}

// ---------- fused gather + dense transform + relu + l2norm (both sides) ----------
// Gather: block edge range split exactly across 4 waves, each wave's range
// split into 8 chains (floor split: lengths differ by <=1). Main loop is
// branchless; per edge: hv = hsrc[(x&0x3FFFF)*64+ln]; ds_add into Xs row.
__global__ __launch_bounds__(256, 4) void transform_fused_kernel(
    const float* __restrict__ hself_u, const float* __restrict__ hsrc_u,
    const int* __restrict__ rowptr_u, const uint2* __restrict__ edges_u,
    const float* __restrict__ WtU, float* __restrict__ out_u,
    const float* __restrict__ hself_i, const float* __restrict__ hsrc_i,
    const int* __restrict__ rowptr_i, const uint2* __restrict__ edges_i,
    const float* __restrict__ WtI, float* __restrict__ out_i,
    int nbu)
{
    __shared__ float Ws[64 * 64];    // 16 KB — one half of Wt at a time
    __shared__ float Xs[64 * 68];    // 17 KB, stride 68
    __shared__ int   rp_s[65];

    const int tid = threadIdx.x;

    const float* hself; const float* hsrc; const int* rowptr;
    const uint2* edges; const float* Wt; float* out; int N; int bb;
    if ((int)blockIdx.x < nbu) {
        hself = hself_u; hsrc = hsrc_u; rowptr = rowptr_u; edges = edges_u;
        Wt = WtU; out = out_u; N = N_USERS; bb = blockIdx.x;
    } else {
        hself = hself_i; hsrc = hsrc_i; rowptr = rowptr_i; edges = edges_i;
        Wt = WtI; out = out_i; N = N_ITEMS; bb = blockIdx.x - nbu;
    }
    const int row0 = bb * 64;

    // ---- stage Ws half A (k=0..63) + self tile + rowptr slice ----
    #pragma unroll
    for (int i = 0; i < 16; ++i) Ws[tid + i * 256] = Wt[tid + i * 256];
    #pragma unroll
    for (int i = 0; i < 16; ++i) {
        int idx = tid + i * 256;
        int rr = idx >> 6, cc = idx & 63;
        int gr = row0 + rr; if (gr > N - 1) gr = N - 1;
        Xs[rr * 68 + cc] = hself[gr * 64 + cc];
    }
    if (tid <= 64) rp_s[tid] = rowptr[min(row0 + tid, N)];
    __syncthreads();

    const int tr = tid >> 3;     // 0..31
    const int tc = tid & 7;      // 0..7
    const int r0 = 2 * tr;

    float acc[2][8];
    #pragma unroll
    for (int j = 0; j < 2; ++j)
        #pragma unroll
        for (int c = 0; c < 8; ++c) acc[j][c] = 0.f;

    // ---- GEMM phase A: self features ----
    #pragma unroll 8
    for (int k = 0; k < 64; ++k) {
        float a0 = Xs[r0 * 68 + k];
        float a1 = Xs[(r0 + 1) * 68 + k];
        float4 b0 = *(const float4*)&Ws[k * 64 + 8 * tc];
        float4 b1 = *(const float4*)&Ws[k * 64 + 8 * tc + 4];
        float b[8] = {b0.x, b0.y, b0.z, b0.w, b1.x, b1.y, b1.z, b1.w};
        #pragma unroll
        for (int c = 0; c < 8; ++c) {
            acc[0][c] = fmaf(a0, b[c], acc[0][c]);
            acc[1][c] = fmaf(a1, b[c], acc[1][c]);
        }
    }
    __syncthreads();   // done with Ws-A and self Xs

    // ---- reload Ws half B; zero Xs ----
    {
        const float4* src = (const float4*)(Wt + 4096);
        float4* dst = (float4*)Ws;
        #pragma unroll
        for (int i = 0; i < 4; ++i) dst[tid + i * 256] = src[tid + i * 256];
        #pragma unroll
        for (int i = 0; i < 17; ++i) Xs[tid + i * 256] = 0.f;   // 17*256 == 64*68
    }
    __syncthreads();

    // ---- checkless edge-balanced gather with per-edge LDS-atomic ----
    {
        const int wv = tid >> 6;
        const int ln = tid & 63;
        const int e0 = rp_s[0];
        const int E  = rp_s[64] - e0;
        const int wbeg = e0 + ((wv * E) >> 2);
        const int wend = e0 + (((wv + 1) * E) >> 2);
        const int L = wend - wbeg;

        int   pos[8], ce[8];
        uint2 ec[8];
        #pragma unroll
        for (int c = 0; c < 8; ++c) {
            pos[c] = wbeg + ((c * L) >> 3);
            ce[c]  = wbeg + (((c + 1) * L) >> 3);
            ec[c]  = edges[pos[c]];               // edges padded +8: safe
        }
        const int Lf = L >> 3;    // min chain length; max is Lf+1

        #pragma unroll 1
        for (int it = 0; it < Lf; ++it) {
            float hv[8], wg[8];
            int   rl[8];
            #pragma unroll
            for (int c = 0; c < 8; ++c) {
                unsigned x = ec[c].x;
                wg[c] = __uint_as_float(ec[c].y);
                rl[c] = (int)(x >> 18);
                hv[c] = hsrc[(int)(x & 0x3FFFFu) * 64 + ln];
            }
            #pragma unroll
            for (int c = 0; c < 8; ++c) {
                ++pos[c];
                ec[c] = edges[pos[c]];            // prefetch next (padded: safe)
            }
            #pragma unroll
            for (int c = 0; c < 8; ++c)
                atomicAdd(&Xs[rl[c] * 68 + ln], wg[c] * hv[c]);
        }
        // masked epilogue: chains of length Lf+1
        {
            #pragma unroll
            for (int c = 0; c < 8; ++c) {
                bool v = pos[c] < ce[c];
                unsigned x = v ? ec[c].x : 0u;    // clamp: poison-safe addrs
                float  w = v ? __uint_as_float(ec[c].y) : 0.f;
                float hv = hsrc[(int)(x & 0x3FFFFu) * 64 + ln];
                atomicAdd(&Xs[(int)(x >> 18) * 68 + ln], w * hv);
            }
        }
    }
    __syncthreads();

    // ---- GEMM phase B: neighbor features ----
    #pragma unroll 8
    for (int k = 0; k < 64; ++k) {
        float a0 = Xs[r0 * 68 + k];
        float a1 = Xs[(r0 + 1) * 68 + k];
        float4 b0 = *(const float4*)&Ws[k * 64 + 8 * tc];
        float4 b1 = *(const float4*)&Ws[k * 64 + 8 * tc + 4];
        float b[8] = {b0.x, b0.y, b0.z, b0.w, b1.x, b1.y, b1.z, b1.w};
        #pragma unroll
        for (int c = 0; c < 8; ++c) {
            acc[0][c] = fmaf(a0, b[c], acc[0][c]);
            acc[1][c] = fmaf(a1, b[c], acc[1][c]);
        }
    }

    // ---- epilogue: relu, row L2 norm (8 lanes per row), store ----
    #pragma unroll
    for (int j = 0; j < 2; ++j) {
        float s = 0.f;
        #pragma unroll
        for (int c = 0; c < 8; ++c) {
            float v = fmaxf(acc[j][c], 0.f);
            acc[j][c] = v;
            s = fmaf(v, v, s);
        }
        s += __shfl_xor(s, 1);
        s += __shfl_xor(s, 2);
        s += __shfl_xor(s, 4);
        float nrm = sqrtf(s);
        float inv = 1.f / fmaxf(nrm, 1e-12f);
        int gr = row0 + r0 + j;
        if (gr < N) {
            float4 o0 = make_float4(acc[j][0]*inv, acc[j][1]*inv, acc[j][2]*inv, acc[j][3]*inv);
            float4 o1 = make_float4(acc[j][4]*inv, acc[j][5]*inv, acc[j][6]*inv, acc[j][7]*inv);
            float* p = out + gr * 64 + 8 * tc;
            *(float4*)p       = o0;
            *(float4*)(p + 4) = o1;
        }
    }
}

extern "C" void kernel_launch(void* const* d_in, const int* in_sizes, int n_in,
                              void* d_out, int out_size, void* d_ws, size_t ws_size,
                              hipStream_t stream)
{
    (void)in_sizes; (void)n_in; (void)out_size; (void)ws_size;

    const float* user_emb = (const float*)d_in[0];
    const float* item_emb = (const float*)d_in[1];
    const float* Wu       = (const float*)d_in[2];
    const float* Wi       = (const float*)d_in[3];
    const int*   u_idx    = (const int*)d_in[4];
    const int*   i_idx    = (const int*)d_in[5];
    const float* w_u2i    = (const float*)d_in[6];
    const float* w_i2u    = (const float*)d_in[7];
    float* out = (float*)d_out;

    float* ws      = (float*)d_ws;
    float* WuT     = ws;                            // 16384
    float* WiT     = WuT + 16384;                   // 16384
    float* hu1     = WiT + 16384;                   // 12,800,000
    float* hi1     = hu1 + N_USERS * 64;            // 6,400,000
    uint2* edges_u = (uint2*)(hi1 + N_ITEMS * 64);  // 3.2M+8 uint2
    uint2* edges_i = edges_u + (N_EDGES + 8);       // 3.2M+8 uint2
    unsigned short* rank_u = (unsigned short*)(edges_i + (N_EDGES + 8));
    unsigned short* rank_i = rank_u + N_EDGES;
    int* rowptr_u = (int*)(rank_i + N_EDGES);       // 200001
    int* rowptr_i = rowptr_u + (N_USERS + 1);       // 100001
    int* deg_u    = rowptr_i + (N_ITEMS + 1);       // 200000
    int* deg_i    = deg_u + N_USERS;                // 100000
    int* bsum_u   = deg_i + N_ITEMS;
    int* bpre_u   = bsum_u + NB_U;
    int* bsum_i   = bpre_u + NB_U;
    int* bpre_i   = bsum_i + NB_I;

    const int tu_blocks = (N_USERS + 63) / 64;        // 3125
    const int ti_blocks = (N_ITEMS + 63) / 64;        // 1563
    const int e2_blocks = (2 * N_EDGES) / 256;        // 25000

    // ---- CSR build (both sides) ----
    wprep_kernel<<<128, 256, 0, stream>>>(Wu, Wi, WuT, WiT);
    hipMemsetAsync(deg_u, 0, (size_t)(N_USERS + N_ITEMS) * 4, stream);
    hist_kernel<<<e2_blocks, 256, 0, stream>>>(u_idx, i_idx, deg_u, deg_i, rank_u, rank_i);
    scanA_kernel<<<NB_U + NB_I, 256, 0, stream>>>(deg_u, deg_i, bsum_u, bsum_i);
    scanB_kernel<<<2, 1024, 0, stream>>>(bsum_u, bpre_u, bsum_i, bpre_i);
    scanC_kernel<<<NB_U + NB_I, 256, 0, stream>>>(deg_u, deg_i, bpre_u, bpre_i, rowptr_u, rowptr_i);
    fill_kernel<<<2048, 256, 0, stream>>>(u_idx, i_idx, w_u2i, w_i2u,
                                          rank_u, rank_i, rowptr_u, rowptr_i,
                                          edges_u, edges_i);

    // ---- layer 0 (u + i in one dispatch) ----
    transform_fused_kernel<<<tu_blocks + ti_blocks, 256, 0, stream>>>(
        user_emb, item_emb, rowptr_u, edges_u, WuT, hu1,
        item_emb, user_emb, rowptr_i, edges_i, WiT, hi1, tu_blocks);

    // ---- layer 1 (u + i in one dispatch) ----
    transform_fused_kernel<<<tu_blocks + ti_blocks, 256, 0, stream>>>(
        hu1, hi1, rowptr_u, edges_u, WuT + 8192, out,
        hi1, hu1, rowptr_i, edges_i, WiT + 8192, out + (size_t)N_USERS * 64, tu_blocks);
}